// Round 6
// baseline (69.420 us; speedup 1.0000x reference)
//
#include <hip/hip_runtime.h>
#include <hip/hip_bf16.h>

// Problem: B=4, LQ=LK=1024, NHEADS=16, DK=64, D_MODEL=1024.
// out[b,i,d] = 0.125 * sum_{n,k} q[b,i,n,k] * T[b,n,k,d] + fc_b[d]
// T[b,n,k,d] = sum_j k[b,j,n,k] * fc_w[d, j*16+n]
// Factored: stage1 T2t[b][d][n*64+k] = Wt[n] @ Kt[n]^T (16 batches, 1024x256x1024)
//           stage2 out[b] = 0.125 * Qb[b] @ T2t[b]^T + bias (4 batches, 1024^3)
// q->bf16 conversion is folded into gemm1's epilogue (streams while blocks drain).
// prep is barrier-free / LDS-free: de-interleave done purely by address mapping.

typedef unsigned short u16;
typedef unsigned int u32;
typedef __bf16 bf16x8 __attribute__((ext_vector_type(8)));
typedef float f32x4 __attribute__((ext_vector_type(4)));
typedef u16 u16x8 __attribute__((ext_vector_type(8)));

__device__ __forceinline__ u16 f2bf(float f) {
  union { float f; unsigned u; } in;
  in.f = f;
  unsigned u = in.u;
  u += 0x7fffu + ((u >> 16) & 1u);  // RNE
  return (u16)(u >> 16);
}

// ---------------- prep: k transpose + fc_w de-interleave, no LDS, no barriers ----
// blocks [0,1024): w-role, d = bid. Wt[n][d][j] = fc_w[d][j*16+n].
//   lane l = (n = l&15, g = l>>4); 8 scalar loads stride 64B inside a
//   wave-shared 2KB window (all lines fully consumed), 1x 16B store
//   (per n-plane: 4 lanes x 16B = 64B contiguous).
// blocks [1024,1088): k-role, (b,n). Kt[n][b*64+kk][j] = k[b][j][n][kk].
//   lane = kk; 8x 256B-coalesced loads across j -> u16x8 row-chunk store.
__global__ __launch_bounds__(256) void prep(const float* __restrict__ k,
                                            const float* __restrict__ w,
                                            u16* __restrict__ Kt,
                                            u16* __restrict__ Wt) {
  const int tid = threadIdx.x;
  const int bid = blockIdx.x;
  const int wv = tid >> 6, lane = tid & 63;

  if (bid < 1024) {
    // ---- w-role: one d-row (64KB read, 32KB write) ----
    const int d = bid;
    const int n = lane & 15, g = lane >> 4;
    const float* src = w + (size_t)d * 16384 + n;
    u16* dst = Wt + (size_t)n * 1048576 + (size_t)d * 1024;
#pragma unroll
    for (int t = 0; t < 8; t += 2) {
      const int j0 = wv * 256 + t * 32 + g * 8;
      const int j1 = j0 + 32;
      float f0[8], f1[8];
#pragma unroll
      for (int e = 0; e < 8; ++e) f0[e] = src[(size_t)(j0 + e) * 16];
#pragma unroll
      for (int e = 0; e < 8; ++e) f1[e] = src[(size_t)(j1 + e) * 16];
      u16x8 o0, o1;
#pragma unroll
      for (int e = 0; e < 8; ++e) o0[e] = f2bf(f0[e]);
#pragma unroll
      for (int e = 0; e < 8; ++e) o1[e] = f2bf(f1[e]);
      *reinterpret_cast<u16x8*>(dst + j0) = o0;
      *reinterpret_cast<u16x8*>(dst + j1) = o1;
    }
  } else {
    // ---- k-role: one (b,n) pair (16KB read, 8KB write per wave-range) ----
    const int e2 = bid - 1024;
    const int b = e2 >> 4, n = e2 & 15;
    const float* src = k + (((size_t)b * 1024) * 16 + n) * 64 + lane;
    u16* dst = Kt + ((size_t)n * 256 + b * 64 + lane) * 1024;
#pragma unroll 2
    for (int t = 0; t < 32; t += 2) {
      const int J0 = wv * 256 + t * 8;
      const int J1 = J0 + 8;
      float f0[8], f1[8];
#pragma unroll
      for (int e = 0; e < 8; ++e) f0[e] = src[(size_t)(J0 + e) * 1024];
#pragma unroll
      for (int e = 0; e < 8; ++e) f1[e] = src[(size_t)(J1 + e) * 1024];
      u16x8 o0, o1;
#pragma unroll
      for (int e = 0; e < 8; ++e) o0[e] = f2bf(f0[e]);
#pragma unroll
      for (int e = 0; e < 8; ++e) o1[e] = f2bf(f1[e]);
      *reinterpret_cast<u16x8*>(dst + J0) = o0;
      *reinterpret_cast<u16x8*>(dst + J1) = o1;
    }
  }
}

// ---------------- pipelined GEMM: C = A @ B^T, K=1024, tile 128x128, BK=64 ----------------
// 4 LDS buffers (128 KB), depth-3 prefetch, 1 barrier per K-step, counted vmcnt.
// XOR-swizzled LDS (both sides: pre-swizzled gload_lds source + swizzled ds_read).
// STAGE 1 additionally streams a 64KB chunk of q -> Qb bf16 in its epilogue.
template <int VM>
__device__ __forceinline__ void waitVm() {
  if constexpr (VM == 16) asm volatile("s_waitcnt vmcnt(16)" ::: "memory");
  else if constexpr (VM == 8) asm volatile("s_waitcnt vmcnt(8)" ::: "memory");
  else asm volatile("s_waitcnt vmcnt(0)" ::: "memory");
}

template <int TN_TILES, int STAGE>
__global__ __launch_bounds__(256, 1) void gemm_bt(const u16* __restrict__ Abase,
                                                  const u16* __restrict__ Bbase,
                                                  u16* __restrict__ CoutBf,
                                                  float* __restrict__ CoutF,
                                                  const float* __restrict__ bias,
                                                  const float* __restrict__ qsrc,
                                                  u16* __restrict__ qdst) {
  __shared__ u16 AB[4][2][128 * 64];  // [buf][A/B][row*64+col], 128 KB
  const int tid = threadIdx.x;
  const int wid = tid >> 6;
  const int lane = tid & 63;
  const int batch = blockIdx.y;
  const int tm = blockIdx.x / TN_TILES;
  const int tn = blockIdx.x % TN_TILES;

  const u16* A = Abase + (size_t)batch * 1048576;
  const u16* B = Bbase + (size_t)batch * ((STAGE == 1) ? 262144 : 1048576);
  const int row0A = tm * 128, row0B = tn * 128;

  const int wr = wid >> 1;
  const int wc = wid & 1;
  const int laneRow = lane & 15;
  const int hi8 = (lane >> 4) * 8;
  const int swz = (lane & 7) * 8;

  f32x4 acc[4][4] = {};

  auto stage = [&](int tIdx) {
    const int kt = tIdx * 64;
    u16* lA = &AB[tIdx & 3][0][0];
    u16* lB = &AB[tIdx & 3][1][0];
#pragma unroll
    for (int i = 0; i < 4; ++i) {
      int p = i * 256 + tid;                  // 16B chunk id, 0..1023
      int r = p >> 3;                         // row 0..127
      int sc = ((p & 7) ^ (r & 7)) * 8;       // swizzled source col (elems)
      const u16* gA = A + (size_t)(row0A + r) * 1024 + kt + sc;
      const u16* gB = B + (size_t)(row0B + r) * 1024 + kt + sc;
      __builtin_amdgcn_global_load_lds(
          (const __attribute__((address_space(1))) void*)gA,
          (__attribute__((address_space(3))) void*)(lA + i * 2048 + wid * 512), 16, 0, 0);
      __builtin_amdgcn_global_load_lds(
          (const __attribute__((address_space(1))) void*)gB,
          (__attribute__((address_space(3))) void*)(lB + i * 2048 + wid * 512), 16, 0, 0);
    }
  };

  auto compute = [&](int tIdx) {
    const u16* At = &AB[tIdx & 3][0][0];
    const u16* Bt = &AB[tIdx & 3][1][0];
    bf16x8 af[2][4], bq[2][4];
#pragma unroll
    for (int kh = 0; kh < 2; ++kh) {
      int cs = (kh * 32 + hi8) ^ swz;  // swizzled read col
#pragma unroll
      for (int mi = 0; mi < 4; ++mi)
        af[kh][mi] = *reinterpret_cast<const bf16x8*>(
            &At[(wr * 64 + mi * 16 + laneRow) * 64 + cs]);
#pragma unroll
      for (int ni = 0; ni < 4; ++ni)
        bq[kh][ni] = *reinterpret_cast<const bf16x8*>(
            &Bt[(wc * 64 + ni * 16 + laneRow) * 64 + cs]);
    }
#pragma unroll
    for (int kh = 0; kh < 2; ++kh)
#pragma unroll
      for (int mi = 0; mi < 4; ++mi)
#pragma unroll
        for (int ni = 0; ni < 4; ++ni)
          acc[mi][ni] = __builtin_amdgcn_mfma_f32_16x16x32_bf16(
              af[kh][mi], bq[kh][ni], acc[mi][ni], 0, 0, 0);
  };

  // prologue: 3 tiles in flight (24 loads/thread outstanding)
  stage(0); stage(1); stage(2);

  for (int t = 0; t < 13; ++t) {
    waitVm<16>();
    __builtin_amdgcn_s_barrier();
    stage(t + 3);
    compute(t);
  }
  waitVm<16>(); __builtin_amdgcn_s_barrier(); compute(13);
  waitVm<8>();  __builtin_amdgcn_s_barrier(); compute(14);
  waitVm<0>();  __builtin_amdgcn_s_barrier(); compute(15);

  // epilogue: D frag layout col=lane&15, row=(lane>>4)*4+q
#pragma unroll
  for (int mi = 0; mi < 4; ++mi) {
#pragma unroll
    for (int ni = 0; ni < 4; ++ni) {
      int colg = tn * 128 + wc * 64 + ni * 16 + laneRow;
#pragma unroll
      for (int qq = 0; qq < 4; ++qq) {
        int rowg = tm * 128 + wr * 64 + mi * 16 + (lane >> 4) * 4 + qq;
        if (STAGE == 1) {
          size_t off = (size_t)(colg >> 6) * 1048576 + (size_t)rowg * 1024 +
                       (size_t)batch * 64 + (colg & 63);
          CoutBf[off] = f2bf(acc[mi][ni][qq]);
        } else {
          CoutF[(size_t)batch * 1048576 + (size_t)rowg * 1024 + colg] =
              acc[mi][ni][qq] * 0.125f + bias[colg];
        }
      }
    }
  }

  // stage1 tail: stream-convert this block's 64KB chunk of q -> Qb
  if (STAGE == 1) {
    const int cb = batch * 16 + blockIdx.x;  // grid (16,16) -> 256 unique
    const float4* src = reinterpret_cast<const float4*>(qsrc) + (size_t)cb * 4096;
    ushort4* dst = reinterpret_cast<ushort4*>(qdst) + (size_t)cb * 4096;
#pragma unroll
    for (int rnd = 0; rnd < 4; ++rnd) {
      float4 r[4];
#pragma unroll
      for (int i = 0; i < 4; ++i) r[i] = src[rnd * 1024 + i * 256 + tid];
#pragma unroll
      for (int i = 0; i < 4; ++i) {
        ushort4 o;
        o.x = f2bf(r[i].x); o.y = f2bf(r[i].y);
        o.z = f2bf(r[i].z); o.w = f2bf(r[i].w);
        dst[rnd * 1024 + i * 256 + tid] = o;
      }
    }
  }
}

extern "C" void kernel_launch(void* const* d_in, const int* in_sizes, int n_in,
                              void* d_out, int out_size, void* d_ws, size_t ws_size,
                              hipStream_t stream) {
  const float* q    = (const float*)d_in[0];
  const float* k    = (const float*)d_in[1];
  // d_in[2] = v — unused by the reference output
  const float* fc_w = (const float*)d_in[3];
  const float* fc_b = (const float*)d_in[4];
  float* out = (float*)d_out;

  char* ws = (char*)d_ws;
  if (ws_size < 58720256) return;  // need 56 MB scratch
  u16* Qb  = (u16*)(ws);             // [4][1024][1024]   8.4 MB
  u16* Kt  = (u16*)(ws + 8388608);   // [16][256][1024]   8.4 MB
  u16* Wt  = (u16*)(ws + 16777216);  // [16][1024][1024] 33.6 MB
  u16* T2t = (u16*)(ws + 50331648);  // [4][1024][1024]   8.4 MB

  prep<<<1088, 256, 0, stream>>>(k, fc_w, Kt, Wt);
  gemm_bt<2, 1><<<dim3(16, 16), 256, 0, stream>>>(Wt, Kt, T2t, nullptr, nullptr, q, Qb);
  gemm_bt<8, 2><<<dim3(64, 4), 256, 0, stream>>>(Qb, T2t, nullptr, out, fc_b, nullptr, nullptr);
}